// Round 1
// baseline (435.216 us; speedup 1.0000x reference)
//
#include <hip/hip_runtime.h>

// ---------- types ----------
using bf16x8 = __attribute__((ext_vector_type(8))) short;   // 8 bf16 (4 VGPRs)
using f32x4  = __attribute__((ext_vector_type(4))) float;   // MFMA C/D frag

__device__ __forceinline__ ushort f2bf(float f) {
    union { float f; unsigned int u; } c; c.f = f;
    unsigned int u = c.u;
    u = (u + 0x7fffu + ((u >> 16) & 1u)) >> 16;   // RNE
    return (ushort)u;
}

// problem constants
constexpr int BB   = 8;      // batch
constexpr int HH   = 8;      // heads
constexpr int TT   = 2048;   // seq
constexpr int DD   = 128;    // head dim == EMB
constexpr int NQKV = 3072;   // 3*H*D
// softmax: p = exp2((s - m) * C2),  C2 = (1/sqrt(128)) * log2(e)
#define C2F (0.08838834764831845f * 1.4426950408889634f)

// ---------- prep: casts + weight transposes ----------
// xb[t][k] = bf16(x[t][k])                     (2,097,152 els, 4/thread -> 524288)
// WqkvT[j][k] = bf16(W{q,k,v}[k][j%1024])      (393,216)
// WoT[e][k] = bf16(Wo[k][e])                   (131,072)
__global__ void prep_kernel(const float* __restrict__ x,
                            const float* __restrict__ Wq, const float* __restrict__ Wk,
                            const float* __restrict__ Wv, const float* __restrict__ Wo,
                            ushort* __restrict__ xb, ushort* __restrict__ WqkvT,
                            ushort* __restrict__ WoT) {
    int t = blockIdx.x * 256 + threadIdx.x;            // 0 .. 1048575
    if (t < 524288) {
        float4 v = ((const float4*)x)[t];
        ushort4 o;
        o.x = f2bf(v.x); o.y = f2bf(v.y); o.z = f2bf(v.z); o.w = f2bf(v.w);
        ((ushort4*)xb)[t] = o;
    } else if (t < 524288 + 393216) {
        int i = t - 524288;
        int j = i >> 7, kk = i & 127;
        const float* W = (j < 1024) ? Wq : ((j < 2048) ? Wk : Wv);
        int jj = j & 1023;
        WqkvT[j * 128 + kk] = f2bf(W[kk * 1024 + jj]);
    } else {
        int i = t - 917504;
        int e = i >> 10, kk = i & 1023;
        WoT[e * 1024 + kk] = f2bf(Wo[kk * 128 + e]);
    }
}

// ---------- QKV GEMM: [16384 x 128] @ [128 x 3072] -> q,k,v [b][h][t][128] ----------
__global__ __launch_bounds__(256, 2)
void qkv_gemm(const ushort* __restrict__ xb, const ushort* __restrict__ WqkvT,
              ushort* __restrict__ q, ushort* __restrict__ k, ushort* __restrict__ v) {
    __shared__ ushort Al[64 * 136];   // A tile, padded stride 136
    __shared__ ushort Bl[64 * 136];   // Bt tile (rows = out cols)
    const int tid = threadIdx.x;
    const int n0 = blockIdx.x * 64, m0 = blockIdx.y * 64;

    for (int s = tid; s < 1024; s += 256) {
        int row = s >> 4, oct = s & 15;
        *(uint4*)&Al[row * 136 + oct * 8] = *(const uint4*)&xb[m0 * 128 + s * 8];
        *(uint4*)&Bl[row * 136 + oct * 8] = *(const uint4*)&WqkvT[n0 * 128 + s * 8];
    }
    __syncthreads();

    const int w = tid >> 6, lane = tid & 63, l15 = lane & 15, g = lane >> 4;
    const int wm = (w & 1) * 32, wn = (w >> 1) * 32;
    f32x4 acc[2][2] = {};

#pragma unroll
    for (int ks = 0; ks < 4; ks++) {
        bf16x8 af[2], bfr[2];
#pragma unroll
        for (int mb = 0; mb < 2; mb++)
            af[mb] = *(const bf16x8*)&Al[(wm + mb * 16 + l15) * 136 + ks * 32 + g * 8];
#pragma unroll
        for (int nb = 0; nb < 2; nb++)
            bfr[nb] = *(const bf16x8*)&Bl[(wn + nb * 16 + l15) * 136 + ks * 32 + g * 8];
#pragma unroll
        for (int mb = 0; mb < 2; mb++)
#pragma unroll
            for (int nb = 0; nb < 2; nb++)
                acc[mb][nb] = __builtin_amdgcn_mfma_f32_16x16x32_bf16(af[mb], bfr[nb], acc[mb][nb], 0, 0, 0);
    }

#pragma unroll
    for (int mb = 0; mb < 2; mb++)
#pragma unroll
        for (int nb = 0; nb < 2; nb++)
#pragma unroll
            for (int r = 0; r < 4; r++) {
                int m = m0 + wm + mb * 16 + g * 4 + r;
                int j = n0 + wn + nb * 16 + l15;
                int which = j >> 10, h = (j >> 7) & 7, e = j & 127;
                int b = m >> 11, t = m & 2047;
                ushort* dst = (which == 0) ? q : ((which == 1) ? k : v);
                dst[((b * HH + h) * TT + t) * DD + e] = f2bf(acc[mb][nb][r]);
            }
}

// ---------- flash attention ----------
// grid: 1024 blocks = (b,h,qt), 128 q-rows per block, 4 waves x 32 rows.
__global__ __launch_bounds__(256, 2)
void attn_kernel(const ushort* __restrict__ q, const ushort* __restrict__ k,
                 const ushort* __restrict__ v, ushort* __restrict__ ao) {
    // smem: Kl (64x136) | Vtl (128x72) | Pl (4 waves x 32x72); Ql (128x136) unions Kl+Vtl
    __shared__ ushort smem[8704 + 9216 + 9216];
    ushort* Kl  = smem;
    ushort* Vtl = smem + 8704;
    ushort* Pl  = smem + 17920;
    ushort* Ql  = smem;                    // 17408 ushorts, dead after q-frag load

    const int idx = blockIdx.x;
    const int qt = idx & 15, h = (idx >> 4) & 7, b = idx >> 7;
    const int t0 = qt * 128;
    const ushort* qg = q + (size_t)((b * HH + h) * TT) * DD;
    const ushort* kg = k + (size_t)((b * HH + h) * TT) * DD;
    const ushort* vg = v + (size_t)((b * HH + h) * TT) * DD;

    const int tid = threadIdx.x, w = tid >> 6, lane = tid & 63;
    const int l15 = lane & 15, g = lane >> 4;

    // ---- stage Q tile (128x128) and pull per-wave A-frags into registers ----
    for (int s = tid; s < 2048; s += 256)
        *(uint4*)&Ql[(s >> 4) * 136 + (s & 15) * 8] = *(const uint4*)&qg[t0 * 128 + s * 8];
    __syncthreads();

    bf16x8 qf[2][4];
#pragma unroll
    for (int mb = 0; mb < 2; mb++)
#pragma unroll
        for (int ks = 0; ks < 4; ks++)
            qf[mb][ks] = *(const bf16x8*)&Ql[(w * 32 + mb * 16 + l15) * 136 + ks * 32 + g * 8];

    f32x4 o[2][8] = {};
    float mprev[2][4], lsum[2][4];
#pragma unroll
    for (int mb = 0; mb < 2; mb++)
#pragma unroll
        for (int r = 0; r < 4; r++) { mprev[mb][r] = -3.0e38f; lsum[mb][r] = 0.0f; }

    for (int n0 = 0; n0 < TT; n0 += 64) {
        __syncthreads();   // previous chunk fully consumed (also covers Q-frag reads, iter 0)

        // stage K chunk (64x128), padded
        for (int s = tid; s < 1024; s += 256)
            *(uint4*)&Kl[(s >> 4) * 136 + (s & 15) * 8] = *(const uint4*)&kg[n0 * 128 + s * 8];

        // stage V chunk transposed: Vtl[e][t_local], stride 72, pair-packed b32 writes
        {
            int p = tid & 31, g16 = tid >> 5;
            int tl = 2 * p, e0 = g16 * 16;
            const ushort* vp = vg + (n0 + tl) * 128 + e0;
            union { uint4 v; ushort s[8]; } r0a, r0b, r1a, r1b;
            r0a.v = *(const uint4*)vp;        r0b.v = *(const uint4*)(vp + 8);
            r1a.v = *(const uint4*)(vp + 128); r1b.v = *(const uint4*)(vp + 136);
#pragma unroll
            for (int j = 0; j < 8; j++)
                *(unsigned int*)&Vtl[(e0 + j) * 72 + tl] =
                    (unsigned int)r0a.s[j] | ((unsigned int)r1a.s[j] << 16);
#pragma unroll
            for (int j = 0; j < 8; j++)
                *(unsigned int*)&Vtl[(e0 + 8 + j) * 72 + tl] =
                    (unsigned int)r0b.s[j] | ((unsigned int)r1b.s[j] << 16);
        }
        __syncthreads();

        // ---- S = Q K^T  (per wave: 32 rows x 64 keys) ----
        f32x4 sf[2][4] = {};
#pragma unroll
        for (int nb = 0; nb < 4; nb++)
#pragma unroll
            for (int ks = 0; ks < 4; ks++) {
                bf16x8 bfr = *(const bf16x8*)&Kl[(nb * 16 + l15) * 136 + ks * 32 + g * 8];
                sf[0][nb] = __builtin_amdgcn_mfma_f32_16x16x32_bf16(qf[0][ks], bfr, sf[0][nb], 0, 0, 0);
                sf[1][nb] = __builtin_amdgcn_mfma_f32_16x16x32_bf16(qf[1][ks], bfr, sf[1][nb], 0, 0, 0);
            }

        // ---- online softmax + P write ----
#pragma unroll
        for (int mb = 0; mb < 2; mb++) {
            float alpha[4];
#pragma unroll
            for (int r = 0; r < 4; r++) {
                float mx = fmaxf(fmaxf(sf[mb][0][r], sf[mb][1][r]), fmaxf(sf[mb][2][r], sf[mb][3][r]));
                mx = fmaxf(mx, __shfl_xor(mx, 1));
                mx = fmaxf(mx, __shfl_xor(mx, 2));
                mx = fmaxf(mx, __shfl_xor(mx, 4));
                mx = fmaxf(mx, __shfl_xor(mx, 8));
                float mnew = fmaxf(mprev[mb][r], mx);
                alpha[r] = __builtin_amdgcn_exp2f((mprev[mb][r] - mnew) * C2F);
                mprev[mb][r] = mnew;
                float rs = 0.0f;
#pragma unroll
                for (int nb = 0; nb < 4; nb++) {
                    float pv = __builtin_amdgcn_exp2f((sf[mb][nb][r] - mnew) * C2F);
                    sf[mb][nb][r] = pv;
                    rs += pv;
                }
                rs += __shfl_xor(rs, 1);
                rs += __shfl_xor(rs, 2);
                rs += __shfl_xor(rs, 4);
                rs += __shfl_xor(rs, 8);
                lsum[mb][r] = lsum[mb][r] * alpha[r] + rs;
            }
#pragma unroll
            for (int eb = 0; eb < 8; eb++)
#pragma unroll
                for (int r = 0; r < 4; r++) o[mb][eb][r] *= alpha[r];
#pragma unroll
            for (int nb = 0; nb < 4; nb++)
#pragma unroll
                for (int r = 0; r < 4; r++)
                    Pl[w * 2304 + (mb * 16 + g * 4 + r) * 72 + nb * 16 + l15] = f2bf(sf[mb][nb][r]);
        }

        // ---- O += P V  (same-wave LDS RAW: DS pipe is in-order per wave) ----
#pragma unroll
        for (int ns = 0; ns < 2; ns++) {
            bf16x8 pa0 = *(const bf16x8*)&Pl[w * 2304 + (l15) * 72 + ns * 32 + g * 8];
            bf16x8 pa1 = *(const bf16x8*)&Pl[w * 2304 + (16 + l15) * 72 + ns * 32 + g * 8];
#pragma unroll
            for (int eb = 0; eb < 8; eb++) {
                bf16x8 vb = *(const bf16x8*)&Vtl[(eb * 16 + l15) * 72 + ns * 32 + g * 8];
                o[0][eb] = __builtin_amdgcn_mfma_f32_16x16x32_bf16(pa0, vb, o[0][eb], 0, 0, 0);
                o[1][eb] = __builtin_amdgcn_mfma_f32_16x16x32_bf16(pa1, vb, o[1][eb], 0, 0, 0);
            }
        }
    }

    // ---- epilogue: normalize and write attn_out[b*T+t][h*128+e] ----
#pragma unroll
    for (int mb = 0; mb < 2; mb++) {
        float inv[4];
#pragma unroll
        for (int r = 0; r < 4; r++) inv[r] = 1.0f / lsum[mb][r];
#pragma unroll
        for (int eb = 0; eb < 8; eb++)
#pragma unroll
            for (int r = 0; r < 4; r++) {
                int m = t0 + w * 32 + mb * 16 + g * 4 + r;
                int col = h * 128 + eb * 16 + l15;
                ao[(size_t)(b * TT + m) * 1024 + col] = f2bf(o[mb][eb][r] * inv[r]);
            }
    }
}

// ---------- out projection: [16384 x 1024] @ [1024 x 128] + bias -> fp32 ----------
__global__ __launch_bounds__(256, 2)
void outproj_gemm(const ushort* __restrict__ ao, const ushort* __restrict__ WoT,
                  const float* __restrict__ bo, float* __restrict__ out) {
    __shared__ ushort Al[64 * 72];
    __shared__ ushort Bl[64 * 72];
    const int tid = threadIdx.x;
    const int n0 = blockIdx.x * 64, m0 = blockIdx.y * 64;
    const int w = tid >> 6, lane = tid & 63, l15 = lane & 15, g = lane >> 4;
    const int wm = (w & 1) * 32, wn = (w >> 1) * 32;
    f32x4 acc[2][2] = {};

    for (int kc = 0; kc < 16; kc++) {
        int k0 = kc * 64;
        __syncthreads();
        for (int s = tid; s < 512; s += 256) {
            int row = s >> 3, oct = s & 7;
            *(uint4*)&Al[row * 72 + oct * 8] = *(const uint4*)&ao[(size_t)(m0 + row) * 1024 + k0 + oct * 8];
            *(uint4*)&Bl[row * 72 + oct * 8] = *(const uint4*)&WoT[(n0 + row) * 1024 + k0 + oct * 8];
        }
        __syncthreads();
#pragma unroll
        for (int ks = 0; ks < 2; ks++) {
            bf16x8 af[2], bfr[2];
#pragma unroll
            for (int mb = 0; mb < 2; mb++)
                af[mb] = *(const bf16x8*)&Al[(wm + mb * 16 + l15) * 72 + ks * 32 + g * 8];
#pragma unroll
            for (int nb = 0; nb < 2; nb++)
                bfr[nb] = *(const bf16x8*)&Bl[(wn + nb * 16 + l15) * 72 + ks * 32 + g * 8];
#pragma unroll
            for (int mb = 0; mb < 2; mb++)
#pragma unroll
                for (int nb = 0; nb < 2; nb++)
                    acc[mb][nb] = __builtin_amdgcn_mfma_f32_16x16x32_bf16(af[mb], bfr[nb], acc[mb][nb], 0, 0, 0);
        }
    }

#pragma unroll
    for (int mb = 0; mb < 2; mb++)
#pragma unroll
        for (int nb = 0; nb < 2; nb++) {
            int j = n0 + wn + nb * 16 + l15;
            float bias = bo[j];
#pragma unroll
            for (int r = 0; r < 4; r++) {
                int m = m0 + wm + mb * 16 + g * 4 + r;
                out[(size_t)m * 128 + j] = acc[mb][nb][r] + bias;
            }
        }
}

// ---------- launch ----------
extern "C" void kernel_launch(void* const* d_in, const int* in_sizes, int n_in,
                              void* d_out, int out_size, void* d_ws, size_t ws_size,
                              hipStream_t stream) {
    const float* x  = (const float*)d_in[0];
    const float* Wq = (const float*)d_in[1];
    const float* Wk = (const float*)d_in[2];
    const float* Wv = (const float*)d_in[3];
    const float* Wo = (const float*)d_in[4];
    const float* bo = (const float*)d_in[5];
    float* out = (float*)d_out;

    char* ws = (char*)d_ws;
    ushort* xb    = (ushort*)(ws);                 //  4,194,304 B
    ushort* WqkvT = (ushort*)(ws + 4194304);       //    786,432 B
    ushort* WoT   = (ushort*)(ws + 4980736);       //    262,144 B
    ushort* qb    = (ushort*)(ws + 5242880);       // 33,554,432 B
    ushort* kb    = (ushort*)(ws + 38797312);      // 33,554,432 B
    ushort* vb    = (ushort*)(ws + 72351744);      // 33,554,432 B
    ushort* ao    = (ushort*)(ws + 105906176);     // 33,554,432 B  (end ~139.5 MB)

    prep_kernel<<<4096, 256, 0, stream>>>(x, Wq, Wk, Wv, Wo, xb, WqkvT, WoT);
    qkv_gemm<<<dim3(48, 256), 256, 0, stream>>>(xb, WqkvT, qb, kb, vb);
    attn_kernel<<<1024, 256, 0, stream>>>(qb, kb, vb, ao);
    outproj_gemm<<<dim3(2, 256), 256, 0, stream>>>(ao, WoT, bo, out);
}